// Round 8
// baseline (159.854 us; speedup 1.0000x reference)
//
#include <hip/hip_runtime.h>

// FeatureWithRelativePosition: fused pairwise-dist -> Linear(4096->64) -> LN -> SiLU
// BS=4, N=4096, FEAT=64. fp32 in/out, bf16 MFMA inner product, fp32 accumulate.
//
// R11: W in REGISTERS (direct global, 1-chunk software pipeline), pos in LDS.
//      R4/R7/R10 all land 29-33us = VALU(13.4) + LDS(16) SERIALIZED: W through
//      LDS forces per-chunk [LDS burst][VALU burst] alternation in every wave.
//      Fix: W per wave per chunk is only 4 dwordx4 from L2-resident Wbt ->
//      prefetch next chunk into 16 VGPRs at iter top; compiler emits the
//      counted vmcnt automatically. LDS in-loop = 6 pos b128 only (7.7us);
//      no DMA, no asm, no in-loop barriers, no cross-wave state.
//      Floor becomes max(VALU, LDS) ~= 14-17us instead of the sum.
//      Dist math restructured into two half-blocks to halve transient VGPRs
//      (R8's spill lesson: keep peak pressure well under 128).

typedef float f32x4 __attribute__((ext_vector_type(4)));
typedef __bf16 bf16x8 __attribute__((ext_vector_type(8)));

union BF8 { bf16x8 v; uint4 u; };

#define N_PTS 4096
#define FEATD 64
#define BK 256
#define NCH (N_PTS / BK)

// ---- pre-pass: W fp32 [64][4096] -> bf16 granule-major Wbt[512][64][8] ----
// uint4 slot (G*64 + f) holds W[f][G*8 .. G*8+7] as bf16.
__global__ void wconv_kernel(const float* __restrict__ W,
                             unsigned short* __restrict__ Wbt) {
  int gid = blockIdx.x * blockDim.x + threadIdx.x;  // 32768 = 64 f * 512 G
  int f = gid >> 9, m8 = gid & 511;
  const float4* src = (const float4*)(W + (size_t)f * N_PTS + m8 * 8);
  float4 a = src[0], b = src[1];
  BF8 o;
  o.v[0] = (__bf16)a.x; o.v[1] = (__bf16)a.y; o.v[2] = (__bf16)a.z; o.v[3] = (__bf16)a.w;
  o.v[4] = (__bf16)b.x; o.v[5] = (__bf16)b.y; o.v[6] = (__bf16)b.z; o.v[7] = (__bf16)b.w;
  ((uint4*)Wbt)[(size_t)m8 * 64 + f] = o.u;
}

// grid = 256 blocks (batch = bid>>6, rowtile = (bid&63)*64), block = 1024 thr.
// wave&1 = rowset (32 rows), wave>>1 = K-slice (granules ksl*4..+3 per chunk).
__global__ __launch_bounds__(1024, 4) void frp_kernel(
    const float* __restrict__ pos, const float* __restrict__ W,
    const float* __restrict__ bias, const float* __restrict__ gamma,
    const float* __restrict__ beta, const unsigned short* __restrict__ Wbt,
    float* __restrict__ out) {
  __shared__ __align__(16) float Px[N_PTS];  // 16 KiB each, SoA
  __shared__ __align__(16) float Py[N_PTS];
  __shared__ __align__(16) float Pz[N_PTS];
  __shared__ f32x4 mbv[4096];                // 64 KiB merge scratch (epilogue)

  const int tid = threadIdx.x;
  const int lane = tid & 63;
  const int wave = tid >> 6;
  const int rs  = wave & 1;        // rowset: rows rs*32 .. rs*32+31
  const int ksl = wave >> 1;       // 0..7: k-slice (granules ksl*4..ksl*4+3)
  const int fx = lane & 15;
  const int q = lane >> 4;

  const int batch = blockIdx.x >> 6;
  const int nb = (blockIdx.x & 63) * 64;
  const float* posB = pos + (size_t)batch * N_PTS * 3;

  // ---- stage ALL positions SoA (once). 1024 thr x 4 pts, float4 in/out. ----
  {
    const float4* p4 = (const float4*)posB;
    float4 f0 = p4[tid * 3 + 0];
    float4 f1 = p4[tid * 3 + 1];
    float4 f2 = p4[tid * 3 + 2];
    ((float4*)Px)[tid] = make_float4(f0.x, f0.w, f1.z, f2.y);
    ((float4*)Py)[tid] = make_float4(f0.y, f1.x, f1.w, f2.z);
    ((float4*)Pz)[tid] = make_float4(f0.z, f1.y, f2.x, f2.w);
  }

  const bool useWb = (Wbt != nullptr);
  const uint4* Wg = (const uint4*)Wbt;
  const int g8 = ksl * 4 + q;          // this lane's granule (8 pts) within chunk

  f32x4 acc[2][4];
#pragma unroll
  for (int a = 0; a < 2; ++a)
#pragma unroll
    for (int t = 0; t < 4; ++t) acc[a][t] = (f32x4){0.f, 0.f, 0.f, 0.f};

  // prologue: W(chunk 0) into registers (in flight across the barrier)
  uint4 bwc[4];
  if (useWb) {
#pragma unroll
    for (int t = 0; t < 4; ++t) bwc[t] = Wg[g8 * 64 + t * 16 + fx];
  }

  __syncthreads();   // pos staged; ONLY barrier until the K-merge

  // this lane's two A-rows (A-frag row = lane&15); read from LDS (broadcast)
  const int nrow0 = nb + rs * 32 + fx;
  const float px0 = Px[nrow0],      py0 = Py[nrow0],      pz0 = Pz[nrow0];
  const float px1 = Px[nrow0 + 16], py1 = Py[nrow0 + 16], pz1 = Pz[nrow0 + 16];

#pragma unroll 2
  for (int c = 0; c < NCH; ++c) {
    // ---- issue W(c+1) loads (wrap on last iter; data valid, unused) ----
    uint4 bwn[4];
    if (useWb) {
      const int Gn = (((c + 1) & (NCH - 1)) * 32 + g8) * 64;
#pragma unroll
      for (int t = 0; t < 4; ++t) bwn[t] = Wg[Gn + t * 16 + fx];
    }

    // ---- dist VALU on LDS pos, two half-blocks (halved transient regs) ----
    const int m4 = c * 64 + g8 * 2;               // f32x4 index into SoA arrays
    bf16x8 af0, af1;
    {
      f32x4 xa = ((const f32x4*)Px)[m4];
      f32x4 ya = ((const f32x4*)Py)[m4];
      f32x4 za = ((const f32x4*)Pz)[m4];
      f32x4 dx = xa - px0, dy = ya - py0, dz = za - pz0;
      f32x4 sq = dx * dx + dy * dy + dz * dz;
#pragma unroll
      for (int j = 0; j < 4; ++j) af0[j] = (__bf16)__builtin_amdgcn_sqrtf(sq[j]);
      dx = xa - px1; dy = ya - py1; dz = za - pz1;
      sq = dx * dx + dy * dy + dz * dz;
#pragma unroll
      for (int j = 0; j < 4; ++j) af1[j] = (__bf16)__builtin_amdgcn_sqrtf(sq[j]);
    }
    {
      f32x4 xb = ((const f32x4*)Px)[m4 + 1];
      f32x4 yb = ((const f32x4*)Py)[m4 + 1];
      f32x4 zb = ((const f32x4*)Pz)[m4 + 1];
      f32x4 dx = xb - px0, dy = yb - py0, dz = zb - pz0;
      f32x4 sq = dx * dx + dy * dy + dz * dz;
#pragma unroll
      for (int j = 0; j < 4; ++j) af0[4 + j] = (__bf16)__builtin_amdgcn_sqrtf(sq[j]);
      dx = xb - px1; dy = yb - py1; dz = zb - pz1;
      sq = dx * dx + dy * dy + dz * dz;
#pragma unroll
      for (int j = 0; j < 4; ++j) af1[4 + j] = (__bf16)__builtin_amdgcn_sqrtf(sq[j]);
    }

    // ---- MFMAs: W(c) regs issued last iter -> compiler emits vmcnt(4) ----
    if (useWb) {
#pragma unroll
      for (int t = 0; t < 4; ++t) {
        BF8 bw;
        bw.u = bwc[t];
        acc[0][t] = __builtin_amdgcn_mfma_f32_16x16x32_bf16(af0, bw.v, acc[0][t], 0, 0, 0);
        acc[1][t] = __builtin_amdgcn_mfma_f32_16x16x32_bf16(af1, bw.v, acc[1][t], 0, 0, 0);
      }
#pragma unroll
      for (int t = 0; t < 4; ++t) bwc[t] = bwn[t];  // renamed away by unroll-2
    } else {
      // fallback: W direct from global fp32 + inline convert
#pragma unroll
      for (int t = 0; t < 4; ++t) {
        const int G = c * 32 + g8;
        const float4* src = (const float4*)(W + (size_t)(t * 16 + fx) * N_PTS + G * 8);
        float4 a4 = src[0], b4 = src[1];
        BF8 bw;
        bw.v[0] = (__bf16)a4.x; bw.v[1] = (__bf16)a4.y; bw.v[2] = (__bf16)a4.z; bw.v[3] = (__bf16)a4.w;
        bw.v[4] = (__bf16)b4.x; bw.v[5] = (__bf16)b4.y; bw.v[6] = (__bf16)b4.z; bw.v[7] = (__bf16)b4.w;
        acc[0][t] = __builtin_amdgcn_mfma_f32_16x16x32_bf16(af0, bw.v, acc[0][t], 0, 0, 0);
        acc[1][t] = __builtin_amdgcn_mfma_f32_16x16x32_bf16(af1, bw.v, acc[1][t], 0, 0, 0);
      }
    }
    // no barrier: no shared state in the loop. Waves free-run.
  }

  // ---- 8-way K-merge via LDS scratch mbv. region w: w*512+(a*4+t)*64+lane ----
  __syncthreads();  // all waves done computing
  if (ksl >= 4) {
    int w = (ksl - 4) * 2 + rs;
#pragma unroll
    for (int a = 0; a < 2; ++a)
#pragma unroll
      for (int t = 0; t < 4; ++t)
        mbv[w * 512 + (a * 4 + t) * 64 + lane] = acc[a][t];
  }
  __syncthreads();
  if (ksl < 4) {
    int w = ksl * 2 + rs;
#pragma unroll
    for (int a = 0; a < 2; ++a)
#pragma unroll
      for (int t = 0; t < 4; ++t)
        acc[a][t] += mbv[w * 512 + (a * 4 + t) * 64 + lane];
  }
  __syncthreads();
  if (ksl >= 1 && ksl < 4) {
    int w = (ksl - 1) * 2 + rs;
#pragma unroll
    for (int a = 0; a < 2; ++a)
#pragma unroll
      for (int t = 0; t < 4; ++t)
        mbv[w * 512 + (a * 4 + t) * 64 + lane] = acc[a][t];
  }
  __syncthreads();
  if (ksl == 0) {
#pragma unroll
    for (int s = 0; s < 3; ++s)
#pragma unroll
      for (int a = 0; a < 2; ++a)
#pragma unroll
        for (int t = 0; t < 4; ++t)
          acc[a][t] += mbv[(s * 2 + rs) * 512 + (a * 4 + t) * 64 + lane];

    // epilogue: bias + LayerNorm(64) + SiLU. C/D layout: col=lane&15, row=q*4+r.
    float bb[4], gg[4], be[4];
#pragma unroll
    for (int t = 0; t < 4; ++t) {
      bb[t] = bias[t * 16 + fx];
      gg[t] = gamma[t * 16 + fx];
      be[t] = beta[t * 16 + fx];
    }
    float* outB = out + ((size_t)batch * N_PTS + nb + rs * 32) * FEATD;
#pragma unroll
    for (int a = 0; a < 2; ++a) {
#pragma unroll
      for (int r = 0; r < 4; ++r) {
        float x[4], d[4];
#pragma unroll
        for (int t = 0; t < 4; ++t) x[t] = acc[a][t][r] + bb[t];
        float s = x[0] + x[1] + x[2] + x[3];
        s += __shfl_xor(s, 1); s += __shfl_xor(s, 2);
        s += __shfl_xor(s, 4); s += __shfl_xor(s, 8);
        float mu = s * (1.f / 64.f);
        float v = 0.f;
#pragma unroll
        for (int t = 0; t < 4; ++t) { d[t] = x[t] - mu; v += d[t] * d[t]; }
        v += __shfl_xor(v, 1); v += __shfl_xor(v, 2);
        v += __shfl_xor(v, 4); v += __shfl_xor(v, 8);
        float rstd = __builtin_amdgcn_rsqf(v * (1.f / 64.f) + 1e-5f);
        float* orow = outB + (a * 16 + q * 4 + r) * FEATD;
#pragma unroll
        for (int t = 0; t < 4; ++t) {
          float xn = d[t] * rstd * gg[t] + be[t];
          float y = xn * (1.f / (1.f + __expf(-xn)));  // SiLU
          orow[t * 16 + fx] = y;
        }
      }
    }
  }
}

extern "C" void kernel_launch(void* const* d_in, const int* in_sizes, int n_in,
                              void* d_out, int out_size, void* d_ws, size_t ws_size,
                              hipStream_t stream) {
  const float* pos   = (const float*)d_in[0];  // (4,4096,3)
  const float* W     = (const float*)d_in[1];  // (64,4096)
  const float* bias  = (const float*)d_in[2];  // (64,)
  const float* gamma = (const float*)d_in[3];  // (64,)
  const float* beta  = (const float*)d_in[4];  // (64,)
  float* out = (float*)d_out;                  // (4,4096,64)

  const size_t wb_bytes = (size_t)FEATD * N_PTS * sizeof(unsigned short);  // 512 KiB
  int use_ws = (d_ws != nullptr && ws_size >= wb_bytes);
  unsigned short* Wbt = use_ws ? (unsigned short*)d_ws : nullptr;

  if (use_ws) {
    wconv_kernel<<<dim3((FEATD * N_PTS / 8) / 256), dim3(256), 0, stream>>>(W, Wbt);
  }
  frp_kernel<<<dim3(256), dim3(1024), 0, stream>>>(pos, W, bias, gamma, beta, Wbt, out);
}